// Round 9
// baseline (116.673 us; speedup 1.0000x reference)
//
#include <hip/hip_runtime.h>
#include <math.h>

// StructureLoss — R16: R13 (best, 100.5) + graph-safe last-block final fusion.
// R15 post-mortem: absmax == reference loss exactly -> out never written ->
// hipLaunchCooperativeKernel silently fails under graph capture. Cooperative
// fusion dead. R16 keeps the R13 kernel byte-identical and appends a
// last-block-done tail: agent-scope release stores of part, ACQ_REL
// agent-scope fetch_add on a counter (release emits vmcnt(0)+L2 writeback,
// acquire invalidates -> correct cross-XCD visibility per G16), and the last
// block runs the old sloss_final body verbatim with agent-scope relaxed
// loads. Counter zeroed by a 4-byte hipMemsetAsync (capture-legal; the
// harness reset uses hipMemsetAsync itself). Replaces the final kernel
// dispatch + gap with a tiny memset dispatch. Same summation order
// everywhere -> absmax 0 preserved.

#define IMG_H 512
#define IMG_W 512
#define NB    32
#define HW    (IMG_H * IMG_W)
#define BANDS 16              // 32-row bands per image
#define NBLK  (NB * BANDS)    // 512 blocks -> 2 per CU
#define NTH   512
#define VST   584             // vls row stride (floats), skewed layout

__device__ __forceinline__ float wave_reduce(float v) {
#pragma unroll
  for (int off = 32; off > 0; off >>= 1) v += __shfl_down(v, off, 64);
  return v;
}

// stage2 for 16 rows starting at vls row 0; consumes XGv/TGv register tiles
#define STAGE2(XGv, TGv)                                                       \
  {                                                                            \
    const float* vb = &vls[row * VST + cb];                                    \
    float q16[16];                                                             \
    {                                                                          \
      float run = 0.f;                                                         \
      _Pragma("unroll")                                                        \
      for (int e = 0; e < 4; ++e) {                                            \
        float4 vv = *(const float4*)(vb + 4 * e);                              \
        q16[4 * e + 0] = run + vv.x;                                           \
        q16[4 * e + 1] = q16[4 * e + 0] + vv.y;                                \
        q16[4 * e + 2] = q16[4 * e + 1] + vv.z;                                \
        q16[4 * e + 3] = q16[4 * e + 2] + vv.w;                                \
        run = q16[4 * e + 3];                                                  \
      }                                                                        \
    }                                                                          \
    {                                                                          \
      float tot = q16[15], ss = tot;                                           \
      _Pragma("unroll")                                                        \
      for (int d = 1; d < 32; d <<= 1) {                                       \
        float uu = __shfl_up(ss, d, 64);                                       \
        if (sub >= d) ss += uu;                                                \
      }                                                                        \
      float pb = ss - tot;                                                     \
      _Pragma("unroll")                                                        \
      for (int j = 0; j < 16; ++j) q16[j] += pb;   /* q16[j] = P[16*sub+j] */  \
    }                                                                          \
    _Pragma("unroll")                                                          \
    for (int e = 0; e < 4; ++e) {                                              \
      float xa[4] = {XGv[e].x, XGv[e].y, XGv[e].z, XGv[e].w};                  \
      float ta[4] = {TGv[e].x, TGv[e].y, TGv[e].z, TGv[e].w};                  \
      _Pragma("unroll")                                                        \
      for (int l = 0; l < 4; ++l) {                                            \
        const int j = 4 * e + l;                                               \
        float hi;                                                              \
        if (j == 0) {                                                          \
          hi = q16[15];                                                        \
        } else {                                                               \
          float gd = __shfl_down(q16[j - 1], 1, 64);                           \
          hi = (sub == 31) ? q16[15] : gd;         /* P[min(c+15,511)] */      \
        }                                                                      \
        float gu = __shfl_up(q16[j], 1, 64);                                   \
        float lo = (sub == 0) ? 0.f : gu;          /* P[c-16] or 0 */          \
        float box = hi - lo;                                                   \
        float tv = ta[l], xv = xa[l];                                          \
        float w   = fmaf(5.0f, fabsf(box * inv_area - tv), 1.0f);              \
        float ez  = __expf(-fabsf(xv));                                        \
        float iv  = 1.0f / (1.0f + ez);                                        \
        float p   = (xv >= 0.f) ? iv : ez * iv;    /* sigmoid(x) */            \
        float bce = fmaxf(xv, 0.f) - xv * tv + __logf(1.0f + ez);              \
        aW  += w;                                                              \
        aWB = fmaf(w, bce, aWB);                                               \
        aI  = fmaf(p * tv, w, aI);                                             \
        aU  = fmaf(p + tv, w, aU);                                             \
      }                                                                        \
    }                                                                          \
  }

// 512 blocks: xcd(8) x k(64); 4 images per XCD, 16 bands per image.
__global__ __launch_bounds__(NTH, 4) void sloss_main(const float* __restrict__ x,
                                                     const float* __restrict__ t,
                                                     float* __restrict__ part,
                                                     unsigned* __restrict__ cnt,
                                                     float* __restrict__ out) {
  __shared__ __align__(16) float vls[16 * VST];   // 37,376 B (only LDS tile)
  __shared__ float red[8][4];
  __shared__ float s2[128];
  __shared__ int   isLast;

  const int tid  = threadIdx.x;
  const int bid  = blockIdx.x;
  const int xcd  = bid & 7;
  const int k    = bid >> 3;               // 0..63
  const int img  = (xcd << 2) | (k >> 4);  // 4 images per XCD
  const int band = k & 15;                 // 16 bands per image
  const int r0   = band * 32;
  const float* tb = t + (size_t)img * HW;
  const float* xb = x + (size_t)img * HW;
  const float* tc = tb + tid;              // phase-1: thread = column tid

  const int li  = tid + 4 * (tid >> 5);    // skewed col index for vls writes
  const int row = tid >> 5;                // stage-2 row 0..15
  const int sub = tid & 31;                // stage-2 16-col chunk 0..31
  const int cb  = 36 * (sub >> 1) + 16 * (sub & 1);
  const float inv_area = 1.0f / 961.0f;

  // ---- warm-up: sum of t rows [r0-15, r0+14] for this column ----
  float sum = 0.f;
  {
    float w[30];
#pragma unroll
    for (int j = 0; j < 30; ++j) {
      int r = r0 - 15 + j;
      w[j] = ((unsigned)r < IMG_H) ? tc[(size_t)r * IMG_W] : 0.f;
    }
#pragma unroll
    for (int j = 0; j < 30; ++j) sum += w[j];
  }

  // ---- issue sub-iter-0 operands: head/tail rows + stage-2 x/t tiles ----
  float hd0[16], tl0[16];
#pragma unroll
  for (int i = 0; i < 16; ++i) {
    int r = r0 + i + 15;
    hd0[i] = ((unsigned)r < IMG_H) ? tc[(size_t)r * IMG_W] : 0.f;
  }
#pragma unroll
  for (int i = 0; i < 16; ++i) {
    int r = r0 + i - 15;
    tl0[i] = ((unsigned)r < IMG_H) ? tc[(size_t)r * IMG_W] : 0.f;
  }
  float4 xg0[4], tg0[4];
  const size_t base0 = (size_t)(r0 + row) * IMG_W + 16 * sub;
#pragma unroll
  for (int e = 0; e < 4; ++e) xg0[e] = *(const float4*)(xb + base0 + 4 * e);
#pragma unroll
  for (int e = 0; e < 4; ++e) tg0[e] = *(const float4*)(tb + base0 + 4 * e);

  float aW = 0.f, aWB = 0.f, aI = 0.f, aU = 0.f;

  // ---- sub-iter 0: march rows r0..r0+15 ----
#pragma unroll
  for (int i = 0; i < 16; ++i) {
    sum += hd0[i];
    vls[i * VST + li] = sum;
    sum -= tl0[i];
  }
  __syncthreads();

  // issue sub-iter-1 phase-1 operands; they fly under stage-2 s0
  float hd1[16], tl1[16];
#pragma unroll
  for (int i = 0; i < 16; ++i) {
    int r = r0 + 16 + i + 15;
    hd1[i] = ((unsigned)r < IMG_H) ? tc[(size_t)r * IMG_W] : 0.f;
  }
#pragma unroll
  for (int i = 0; i < 16; ++i) {
    int r = r0 + 16 + i - 15;
    tl1[i] = ((unsigned)r < IMG_H) ? tc[(size_t)r * IMG_W] : 0.f;
  }

  STAGE2(xg0, tg0)
  __syncthreads();

  // ---- sub-iter 1: march rows r0+16..r0+31; stage-2 tiles issued early ----
  float4 xg1[4], tg1[4];
  const size_t base1 = base0 + (size_t)16 * IMG_W;
#pragma unroll
  for (int e = 0; e < 4; ++e) xg1[e] = *(const float4*)(xb + base1 + 4 * e);
#pragma unroll
  for (int e = 0; e < 4; ++e) tg1[e] = *(const float4*)(tb + base1 + 4 * e);
#pragma unroll
  for (int i = 0; i < 16; ++i) {
    sum += hd1[i];
    vls[i * VST + li] = sum;
    sum -= tl1[i];
  }
  __syncthreads();

  STAGE2(xg1, tg1)

  // ---- block reduction -> part (agent-scope release stores) ----
  aW  = wave_reduce(aW);
  aWB = wave_reduce(aWB);
  aI  = wave_reduce(aI);
  aU  = wave_reduce(aU);
  const int wv = tid >> 6, ln = tid & 63;
  if (ln == 0) { red[wv][0] = aW; red[wv][1] = aWB; red[wv][2] = aI; red[wv][3] = aU; }
  __syncthreads();
  if (tid < 4) {
    float v = 0.f;
#pragma unroll
    for (int w8 = 0; w8 < 8; ++w8) v += red[w8][tid];
    __hip_atomic_store(&part[(img * BANDS + band) * 4 + tid], v,
                       __ATOMIC_RELEASE, __HIP_MEMORY_SCOPE_AGENT);
  }
  __syncthreads();

  // ---- last-block-done detection (device-scope; cross-XCD safe) ----
  if (tid == 0) {
    unsigned old = __hip_atomic_fetch_add(cnt, 1u, __ATOMIC_ACQ_REL,
                                          __HIP_MEMORY_SCOPE_AGENT);
    isLast = (old == (unsigned)(NBLK - 1));
  }
  __syncthreads();

  if (isLast) {
    // old sloss_final body verbatim; part read with coherent agent loads
    if (tid < 128) {
      int fimg = tid >> 2, q = tid & 3;
      float v = 0.f;
#pragma unroll 4
      for (int g = 0; g < BANDS; ++g)
        v += __hip_atomic_load(&part[((fimg << 4) + g) * 4 + q],
                               __ATOMIC_RELAXED, __HIP_MEMORY_SCOPE_AGENT);
      s2[tid] = v;
    }
    __syncthreads();
    if (tid < 128) {
      float loss = 0.f;
      if (tid < NB) {
        float fW  = s2[tid * 4 + 0];
        float fWB = s2[tid * 4 + 1];
        float fI  = s2[tid * 4 + 2];
        float fU  = s2[tid * 4 + 3];
        loss = fWB / fW + 1.0f - (fI + 1.0f) / (fU - fI + 1.0f);
      }
      loss = wave_reduce(loss);
      if (tid == 0) out[0] = loss * (1.0f / (float)NB);
    }
  }
}

extern "C" void kernel_launch(void* const* d_in, const int* in_sizes, int n_in,
                              void* d_out, int out_size, void* d_ws, size_t ws_size,
                              hipStream_t stream) {
  const float* x = (const float*)d_in[0];
  const float* t = (const float*)d_in[1];
  float*    part = (float*)d_ws;                    // 512 x 4 floats
  unsigned* cnt  = (unsigned*)((char*)d_ws + 8192); // 4-byte arrival counter

  hipMemsetAsync((void*)cnt, 0, sizeof(unsigned), stream);  // capture-legal
  sloss_main<<<NBLK, NTH, 0, stream>>>(x, t, part, cnt, (float*)d_out);
}

// Round 10
// 101.982 us; speedup vs baseline: 1.1441x; 1.1441x over previous
//
#include <hip/hip_runtime.h>
#include <math.h>

// StructureLoss — R17: revert to R13 verbatim (best measured, 100.5 us).
// Final ledger: R13's structure — 512 blocks (2/CU, XCD-swizzled 32-row
// bands) x 512 thr, thread-per-col register running sum from global, 37.4KB
// skewed vls LDS, phase-interleaved loads, separate tiny final kernel — beat
// every alternative tried in six directions:
//   R8/R9  mono-block 149KB LDS window: barrier-locked, all pipes idle (-4%)
//   R10/R11 S-through-global transpose: +10-12 us round-trip
//   R12    de-drained barriers: neutral (barrier texture is noise)
//   R14    register-tail reuse + traw relay: VGPR 88->64, load-issue
//          serialization, main 42.6 us (+5%)
//   R15    cooperative main+final fusion: hipLaunchCooperativeKernel fails
//          silently under graph capture (out never written)
//   R16    atomic last-block fusion: VGPR 88->64 again + ACQ_REL tail
//          drains, main 46-60 us (+16%)
// Remaining wall time = fixed 268MB harness poison-fill (41 us) + ~20 us
// dispatch overhead (proven non-removable) + main (<41 us, FETCH ~40MB vs
// 67MB unique bytes, bank-conflict 0). Controllable region is within
// ~10-15% of its practical floor.

#define IMG_H 512
#define IMG_W 512
#define NB    32
#define HW    (IMG_H * IMG_W)
#define BANDS 16              // 32-row bands per image
#define NBLK  (NB * BANDS)    // 512 blocks -> 2 per CU
#define NTH   512
#define VST   584             // vls row stride (floats), skewed layout

__device__ __forceinline__ float wave_reduce(float v) {
#pragma unroll
  for (int off = 32; off > 0; off >>= 1) v += __shfl_down(v, off, 64);
  return v;
}

// stage2 for 16 rows starting at vls row 0; consumes XGv/TGv register tiles
#define STAGE2(XGv, TGv)                                                       \
  {                                                                            \
    const float* vb = &vls[row * VST + cb];                                    \
    float q16[16];                                                             \
    {                                                                          \
      float run = 0.f;                                                         \
      _Pragma("unroll")                                                        \
      for (int e = 0; e < 4; ++e) {                                            \
        float4 vv = *(const float4*)(vb + 4 * e);                              \
        q16[4 * e + 0] = run + vv.x;                                           \
        q16[4 * e + 1] = q16[4 * e + 0] + vv.y;                                \
        q16[4 * e + 2] = q16[4 * e + 1] + vv.z;                                \
        q16[4 * e + 3] = q16[4 * e + 2] + vv.w;                                \
        run = q16[4 * e + 3];                                                  \
      }                                                                        \
    }                                                                          \
    {                                                                          \
      float tot = q16[15], ss = tot;                                           \
      _Pragma("unroll")                                                        \
      for (int d = 1; d < 32; d <<= 1) {                                       \
        float uu = __shfl_up(ss, d, 64);                                       \
        if (sub >= d) ss += uu;                                                \
      }                                                                        \
      float pb = ss - tot;                                                     \
      _Pragma("unroll")                                                        \
      for (int j = 0; j < 16; ++j) q16[j] += pb;   /* q16[j] = P[16*sub+j] */  \
    }                                                                          \
    _Pragma("unroll")                                                          \
    for (int e = 0; e < 4; ++e) {                                              \
      float xa[4] = {XGv[e].x, XGv[e].y, XGv[e].z, XGv[e].w};                  \
      float ta[4] = {TGv[e].x, TGv[e].y, TGv[e].z, TGv[e].w};                  \
      _Pragma("unroll")                                                        \
      for (int l = 0; l < 4; ++l) {                                            \
        const int j = 4 * e + l;                                               \
        float hi;                                                              \
        if (j == 0) {                                                          \
          hi = q16[15];                                                        \
        } else {                                                               \
          float gd = __shfl_down(q16[j - 1], 1, 64);                           \
          hi = (sub == 31) ? q16[15] : gd;         /* P[min(c+15,511)] */      \
        }                                                                      \
        float gu = __shfl_up(q16[j], 1, 64);                                   \
        float lo = (sub == 0) ? 0.f : gu;          /* P[c-16] or 0 */          \
        float box = hi - lo;                                                   \
        float tv = ta[l], xv = xa[l];                                          \
        float w   = fmaf(5.0f, fabsf(box * inv_area - tv), 1.0f);              \
        float ez  = __expf(-fabsf(xv));                                        \
        float iv  = 1.0f / (1.0f + ez);                                        \
        float p   = (xv >= 0.f) ? iv : ez * iv;    /* sigmoid(x) */            \
        float bce = fmaxf(xv, 0.f) - xv * tv + __logf(1.0f + ez);              \
        aW  += w;                                                              \
        aWB = fmaf(w, bce, aWB);                                               \
        aI  = fmaf(p * tv, w, aI);                                             \
        aU  = fmaf(p + tv, w, aU);                                             \
      }                                                                        \
    }                                                                          \
  }

// 512 blocks: xcd(8) x k(64); 4 images per XCD, 16 bands per image.
__global__ __launch_bounds__(NTH, 4) void sloss_main(const float* __restrict__ x,
                                                     const float* __restrict__ t,
                                                     float* __restrict__ part) {
  __shared__ __align__(16) float vls[16 * VST];   // 37,376 B (only LDS tile)
  __shared__ float red[8][4];

  const int tid  = threadIdx.x;
  const int bid  = blockIdx.x;
  const int xcd  = bid & 7;
  const int k    = bid >> 3;               // 0..63
  const int img  = (xcd << 2) | (k >> 4);  // 4 images per XCD
  const int band = k & 15;                 // 16 bands per image
  const int r0   = band * 32;
  const float* tb = t + (size_t)img * HW;
  const float* xb = x + (size_t)img * HW;
  const float* tc = tb + tid;              // phase-1: thread = column tid

  const int li  = tid + 4 * (tid >> 5);    // skewed col index for vls writes
  const int row = tid >> 5;                // stage-2 row 0..15
  const int sub = tid & 31;                // stage-2 16-col chunk 0..31
  const int cb  = 36 * (sub >> 1) + 16 * (sub & 1);
  const float inv_area = 1.0f / 961.0f;

  // ---- warm-up: sum of t rows [r0-15, r0+14] for this column ----
  float sum = 0.f;
  {
    float w[30];
#pragma unroll
    for (int j = 0; j < 30; ++j) {
      int r = r0 - 15 + j;
      w[j] = ((unsigned)r < IMG_H) ? tc[(size_t)r * IMG_W] : 0.f;
    }
#pragma unroll
    for (int j = 0; j < 30; ++j) sum += w[j];
  }

  // ---- issue sub-iter-0 operands: head/tail rows + stage-2 x/t tiles ----
  float hd0[16], tl0[16];
#pragma unroll
  for (int i = 0; i < 16; ++i) {
    int r = r0 + i + 15;
    hd0[i] = ((unsigned)r < IMG_H) ? tc[(size_t)r * IMG_W] : 0.f;
  }
#pragma unroll
  for (int i = 0; i < 16; ++i) {
    int r = r0 + i - 15;
    tl0[i] = ((unsigned)r < IMG_H) ? tc[(size_t)r * IMG_W] : 0.f;
  }
  float4 xg0[4], tg0[4];
  const size_t base0 = (size_t)(r0 + row) * IMG_W + 16 * sub;
#pragma unroll
  for (int e = 0; e < 4; ++e) xg0[e] = *(const float4*)(xb + base0 + 4 * e);
#pragma unroll
  for (int e = 0; e < 4; ++e) tg0[e] = *(const float4*)(tb + base0 + 4 * e);

  float aW = 0.f, aWB = 0.f, aI = 0.f, aU = 0.f;

  // ---- sub-iter 0: march rows r0..r0+15 ----
#pragma unroll
  for (int i = 0; i < 16; ++i) {
    sum += hd0[i];
    vls[i * VST + li] = sum;
    sum -= tl0[i];
  }
  __syncthreads();

  // issue sub-iter-1 phase-1 operands; they fly under stage-2 s0
  float hd1[16], tl1[16];
#pragma unroll
  for (int i = 0; i < 16; ++i) {
    int r = r0 + 16 + i + 15;
    hd1[i] = ((unsigned)r < IMG_H) ? tc[(size_t)r * IMG_W] : 0.f;
  }
#pragma unroll
  for (int i = 0; i < 16; ++i) {
    int r = r0 + 16 + i - 15;
    tl1[i] = ((unsigned)r < IMG_H) ? tc[(size_t)r * IMG_W] : 0.f;
  }

  STAGE2(xg0, tg0)
  __syncthreads();

  // ---- sub-iter 1: march rows r0+16..r0+31; stage-2 tiles issued early ----
  float4 xg1[4], tg1[4];
  const size_t base1 = base0 + (size_t)16 * IMG_W;
#pragma unroll
  for (int e = 0; e < 4; ++e) xg1[e] = *(const float4*)(xb + base1 + 4 * e);
#pragma unroll
  for (int e = 0; e < 4; ++e) tg1[e] = *(const float4*)(tb + base1 + 4 * e);
#pragma unroll
  for (int i = 0; i < 16; ++i) {
    sum += hd1[i];
    vls[i * VST + li] = sum;
    sum -= tl1[i];
  }
  __syncthreads();

  STAGE2(xg1, tg1)

  // ---- block reduction ----
  aW  = wave_reduce(aW);
  aWB = wave_reduce(aWB);
  aI  = wave_reduce(aI);
  aU  = wave_reduce(aU);
  const int wv = tid >> 6, ln = tid & 63;
  if (ln == 0) { red[wv][0] = aW; red[wv][1] = aWB; red[wv][2] = aI; red[wv][3] = aU; }
  __syncthreads();
  if (tid < 4) {
    float v = 0.f;
#pragma unroll
    for (int w8 = 0; w8 < 8; ++w8) v += red[w8][tid];
    part[(img * BANDS + band) * 4 + tid] = v;
  }
}

// ---- finalize: reduce 512 block-partials -> scalar loss ----
__global__ void sloss_final(const float* __restrict__ part,
                            float* __restrict__ out) {
  __shared__ float s[128];
  int tid = threadIdx.x;          // 128 threads
  int img = tid >> 2, q = tid & 3;
  float v = 0.f;
#pragma unroll 4
  for (int g = 0; g < BANDS; ++g) v += part[((img << 4) + g) * 4 + q];
  s[tid] = v;
  __syncthreads();
  float loss = 0.f;
  if (tid < NB) {
    float aW  = s[tid * 4 + 0];
    float aWB = s[tid * 4 + 1];
    float aI  = s[tid * 4 + 2];
    float aU  = s[tid * 4 + 3];
    loss = aWB / aW + 1.0f - (aI + 1.0f) / (aU - aI + 1.0f);
  }
  loss = wave_reduce(loss);
  if (tid == 0) out[0] = loss * (1.0f / (float)NB);
}

extern "C" void kernel_launch(void* const* d_in, const int* in_sizes, int n_in,
                              void* d_out, int out_size, void* d_ws, size_t ws_size,
                              hipStream_t stream) {
  const float* x = (const float*)d_in[0];
  const float* t = (const float*)d_in[1];
  float* part = (float*)d_ws;     // 512 x 4 floats, fully overwritten

  sloss_main<<<NBLK, NTH, 0, stream>>>(x, t, part);
  sloss_final<<<1, 128, 0, stream>>>(part, (float*)d_out);
}